// Round 1
// baseline (304.679 us; speedup 1.0000x reference)
//
#include <hip/hip_runtime.h>
#include <hip/hip_bf16.h>
#include <cstdint>

// Problem: B=4, S=1024, D=1024, H=16, DK=64.
// Outputs: out [4,1024,1024] f32, attn [4,16,1024,1024] f32, concatenated in d_out.
#define NB 4
#define NS 1024
#define ND 1024
#define NH 16
#define NDK 64
#define NBH 64  // NB*NH

typedef unsigned short u16;
typedef __attribute__((ext_vector_type(8))) short short8;   // 8 x bf16 bits (4 VGPRs) - MFMA A/B frag
typedef __attribute__((ext_vector_type(4))) float f32x4;    // MFMA C/D frag
typedef __attribute__((ext_vector_type(4))) unsigned short u16x4;

__device__ __forceinline__ u16 f2bf(float x) {
  unsigned u = __builtin_bit_cast(unsigned, x);
  return (u16)((u + 0x7fffu + ((u >> 16) & 1u)) >> 16);  // RNE
}

__device__ __forceinline__ void async16(u16* lds_dst, const u16* gsrc) {
  // global -> LDS direct copy, 16B per lane; lds_dst must be wave-uniform.
  __builtin_amdgcn_global_load_lds(
      (const __attribute__((address_space(1))) void*)gsrc,
      (__attribute__((address_space(3))) void*)lds_dst, 16, 0, 0);
}

// ---------------- f32 -> bf16 conversion prepass ----------------
struct CvtArgs {
  const float* src[7];
  u16* dst[7];
  int n4[7];  // float4 count per segment
};

__global__ __launch_bounds__(256) void cvt_k(CvtArgs a) {
  const int seg = blockIdx.y;
  const float* s = a.src[seg];
  u16* d = a.dst[seg];
  const int n4 = a.n4[seg];
  for (int i = blockIdx.x * 256 + threadIdx.x; i < n4; i += gridDim.x * 256) {
    float4 v = *(const float4*)&s[(size_t)i * 4];
    u16x4 pk = {f2bf(v.x), f2bf(v.y), f2bf(v.z), f2bf(v.w)};
    *(u16x4*)&d[(size_t)i * 4] = pk;
  }
}

// ---------------- common GEMM-BT core: 128x128 tile, BK=64, 4 waves (2x2) ----------------
// A: [M, LDA] bf16 row-major (K contiguous); BT: [N, LDB] bf16 row-major (K contiguous).
// Each wave computes a 64x64 sub-tile as 4x4 frags of 16x16, mfma_f32_16x16x32_bf16.
template <int KTILES, int LDA, int LDB>
__device__ __forceinline__ void gemm_bt_core(const u16* __restrict__ A,
                                             const u16* __restrict__ BT,
                                             u16* As, u16* Bs, f32x4 (&acc)[4][4],
                                             int bm0, int bn0, int wave, int lane) {
  const int lrow = lane & 15;
  const int lkg = lane >> 4;
  const int wm = wave >> 1, wn = wave & 1;
#pragma unroll 1
  for (int t = 0; t < KTILES; ++t) {
    const int k0 = t * 64;
#pragma unroll
    for (int j = 0; j < 4; ++j) {
      const int c = (wave * 4 + j) * 64 + lane;   // 16B chunk id in [0,1024)
      const int row = c >> 3;                     // 64 elems (128B) per row
      const int col = (c & 7) * 8;
      async16(&As[(wave * 4 + j) * 512], A + (size_t)(bm0 + row) * LDA + k0 + col);
      async16(&Bs[(wave * 4 + j) * 512], BT + (size_t)(bn0 + row) * LDB + k0 + col);
    }
    asm volatile("s_waitcnt vmcnt(0)" ::: "memory");
    __syncthreads();
#pragma unroll
    for (int kk = 0; kk < 2; ++kk) {
      short8 av[4], bv[4];
#pragma unroll
      for (int i = 0; i < 4; ++i)
        av[i] = *(const short8*)&As[(wm * 64 + i * 16 + lrow) * 64 + kk * 32 + lkg * 8];
#pragma unroll
      for (int j = 0; j < 4; ++j)
        bv[j] = *(const short8*)&Bs[(wn * 64 + j * 16 + lrow) * 64 + kk * 32 + lkg * 8];
#pragma unroll
      for (int i = 0; i < 4; ++i)
#pragma unroll
        for (int j = 0; j < 4; ++j)
          acc[i][j] = __builtin_amdgcn_mfma_f32_16x16x32_bf16(av[i], bv[j], acc[i][j], 0, 0, 0);
    }
    __syncthreads();
  }
}

// ---------------- QKV projection (z = 0:q, 1:k, 2:v) ----------------
struct ProjArgs {
  const u16* A[3];
  const u16* W[3];
  const float* bias[3];
  u16* dst[3];
};

__global__ __launch_bounds__(256, 2) void proj_gemm(ProjArgs pa) {
  const int z = blockIdx.z;
  const u16* A = pa.A[z];
  const u16* BT = pa.W[z];
  const float* bias = pa.bias[z];
  u16* dst = pa.dst[z];

  __shared__ u16 As[128 * 64];
  __shared__ u16 Bs[128 * 64];
  const int tid = threadIdx.x, wave = tid >> 6, lane = tid & 63;
  const int lrow = lane & 15, lkg = lane >> 4;
  const int wm = wave >> 1, wn = wave & 1;
  const int bm0 = blockIdx.x * 128, bn0 = blockIdx.y * 128;

  f32x4 acc[4][4] = {};
  gemm_bt_core<16, ND, ND>(A, BT, As, Bs, acc, bm0, bn0, wave, lane);

  // Epilogue: C row m = global token (b*S+s), col n = h*64+dk.
#pragma unroll
  for (int i = 0; i < 4; ++i) {
#pragma unroll
    for (int j = 0; j < 4; ++j) {
      const int m0 = bm0 + wm * 64 + i * 16 + lkg * 4;  // 4-aligned
      const int n = bn0 + wn * 64 + j * 16 + lrow;
      const float bn_ = bias[n];
      const int b = m0 >> 10;
      const int h = n >> 6, dk = n & 63;
      if (z < 2) {
        // q/k head layout: [B,H,S,DK]
#pragma unroll
        for (int r = 0; r < 4; ++r) {
          const int s = (m0 + r) & 1023;
          dst[(((size_t)(b * NH + h)) * NS + s) * NDK + dk] = f2bf(acc[i][j][r] + bn_);
        }
      } else {
        // v transposed: [B,H,DK,S]
        const int s0 = m0 & 1023;
        u16x4 pk;
#pragma unroll
        for (int r = 0; r < 4; ++r) pk[r] = f2bf(acc[i][j][r] + bn_);
        *(u16x4*)&dst[(((size_t)(b * NH + h)) * NDK + dk) * NS + s0] = pk;
      }
    }
  }
}

// ---------------- scores = q k^T / 8 (lower-triangular blocks only) ----------------
__global__ __launch_bounds__(256, 2) void qk_gemm(const u16* __restrict__ qh,
                                                  const u16* __restrict__ kh,
                                                  float* __restrict__ attn) {
  const int mt = blockIdx.x, nt = blockIdx.y, bh = blockIdx.z;
  if (nt > mt) return;  // fully-masked block; softmax never reads k>q
  const u16* A = qh + (size_t)bh * NS * NDK;
  const u16* BT = kh + (size_t)bh * NS * NDK;
  float* out = attn + (size_t)bh * NS * NS;

  __shared__ u16 As[128 * 64];
  __shared__ u16 Bs[128 * 64];
  const int tid = threadIdx.x, wave = tid >> 6, lane = tid & 63;
  const int lrow = lane & 15, lkg = lane >> 4;
  const int wm = wave >> 1, wn = wave & 1;
  const int bm0 = mt * 128, bn0 = nt * 128;

  f32x4 acc[4][4] = {};
  gemm_bt_core<1, NDK, NDK>(A, BT, As, Bs, acc, bm0, bn0, wave, lane);

#pragma unroll
  for (int i = 0; i < 4; ++i) {
#pragma unroll
    for (int j = 0; j < 4; ++j) {
      const int m0 = bm0 + wm * 64 + i * 16 + lkg * 4;
      const int n = bn0 + wn * 64 + j * 16 + lrow;
#pragma unroll
      for (int r = 0; r < 4; ++r)
        out[(size_t)(m0 + r) * NS + n] = acc[i][j][r] * 0.125f;
    }
  }
}

// ---------------- causal row softmax (in-place on d_out attn region) ----------------
__global__ __launch_bounds__(256) void softmax_k(float* __restrict__ attn) {
  const int wave = threadIdx.x >> 6, lane = threadIdx.x & 63;
  const size_t row = (size_t)blockIdx.x * 4 + wave;  // [0, 65536)
  const int q = (int)(row & (NS - 1));
  const int L = q + 1;
  float* p = attn + row * NS;

  float4 v[4];
  float mx = -1e30f;
#pragma unroll
  for (int t = 0; t < 4; ++t) {
    const int f = t * 64 + lane;
    v[t] = *(const float4*)&p[f * 4];
#pragma unroll
    for (int e = 0; e < 4; ++e) {
      const int col = f * 4 + e;
      const float val = (col < L) ? ((const float*)&v[t])[e] : -1e30f;
      mx = fmaxf(mx, val);
    }
  }
#pragma unroll
  for (int o = 32; o; o >>= 1) mx = fmaxf(mx, __shfl_xor(mx, o, 64));

  float sum = 0.f;
  float4 o4[4];
#pragma unroll
  for (int t = 0; t < 4; ++t) {
    const int f = t * 64 + lane;
#pragma unroll
    for (int e = 0; e < 4; ++e) {
      const int col = f * 4 + e;
      const float ex = (col < L) ? __expf(((const float*)&v[t])[e] - mx) : 0.f;
      ((float*)&o4[t])[e] = ex;
      sum += ex;
    }
  }
#pragma unroll
  for (int o = 32; o; o >>= 1) sum += __shfl_xor(sum, o, 64);
  const float inv = 1.0f / sum;
#pragma unroll
  for (int t = 0; t < 4; ++t) {
    const int f = t * 64 + lane;
    float4 w = o4[t];
    w.x *= inv; w.y *= inv; w.z *= inv; w.w *= inv;
    *(float4*)&p[f * 4] = w;
  }
}

// ---------------- x = attn @ v (per head), triangular K loop ----------------
__global__ __launch_bounds__(256, 2) void pv_gemm(const float* __restrict__ attn,
                                                  const u16* __restrict__ vT,
                                                  u16* __restrict__ xh) {
  const int mt = blockIdx.x, bh = blockIdx.y;
  const float* Ah = attn + (size_t)bh * NS * NS;
  const u16* BTh = vT + (size_t)bh * NS * NDK;  // [DK, S] row-major

  __shared__ u16 As[128 * 64];  // attn tile, bf16
  __shared__ u16 Bs[64 * 64];   // vT tile
  const int tid = threadIdx.x, wave = tid >> 6, lane = tid & 63;
  const int lrow = lane & 15, lkg = lane >> 4;

  f32x4 acc[2][4] = {};
  const int nkt = (mt + 1) * 2;  // k-tiles of 64 covering k <= q
#pragma unroll 1
  for (int t = 0; t < nkt; ++t) {
    const int k0 = t * 64;
    // stage B (vT rows = dk, cols = k): 8KB via global_load_lds
#pragma unroll
    for (int j = 0; j < 2; ++j) {
      const int c = (wave * 2 + j) * 64 + lane;  // [0,512)
      const int row = c >> 3, col = (c & 7) * 8;
      async16(&Bs[(wave * 2 + j) * 512], BTh + (size_t)row * NS + k0 + col);
    }
    // stage A (attn f32 -> bf16), reg-staged
#pragma unroll
    for (int i = 0; i < 8; ++i) {
      const int f = tid + i * 256;  // float4 id in [0,2048)
      const int e = f * 4;
      const int row = e >> 6, col = e & 63;
      float4 x4 = *(const float4*)&Ah[(size_t)(mt * 128 + row) * NS + k0 + col];
      u16x4 pk = {f2bf(x4.x), f2bf(x4.y), f2bf(x4.z), f2bf(x4.w)};
      *(u16x4*)&As[e] = pk;
    }
    asm volatile("s_waitcnt vmcnt(0)" ::: "memory");
    __syncthreads();
#pragma unroll
    for (int kk = 0; kk < 2; ++kk) {
      short8 av[2], bv[4];
#pragma unroll
      for (int i = 0; i < 2; ++i)
        av[i] = *(const short8*)&As[(wave * 32 + i * 16 + lrow) * 64 + kk * 32 + lkg * 8];
#pragma unroll
      for (int j = 0; j < 4; ++j)
        bv[j] = *(const short8*)&Bs[(j * 16 + lrow) * 64 + kk * 32 + lkg * 8];
#pragma unroll
      for (int i = 0; i < 2; ++i)
#pragma unroll
        for (int j = 0; j < 4; ++j)
          acc[i][j] = __builtin_amdgcn_mfma_f32_16x16x32_bf16(av[i], bv[j], acc[i][j], 0, 0, 0);
    }
    __syncthreads();
  }
  // epilogue: x in [B,S,D] bf16
  const int b = bh >> 4, h = bh & 15;
#pragma unroll
  for (int i = 0; i < 2; ++i) {
#pragma unroll
    for (int j = 0; j < 4; ++j) {
      const int s0 = mt * 128 + wave * 32 + i * 16 + lkg * 4;
      const int dk = j * 16 + lrow;
#pragma unroll
      for (int r = 0; r < 4; ++r)
        xh[((size_t)(b * NS + s0 + r)) * ND + h * NDK + dk] = f2bf(acc[i][j][r]);
    }
  }
}

// ---------------- out = x @ Wo^T + bo ----------------
__global__ __launch_bounds__(256, 2) void out_gemm(const u16* __restrict__ xh,
                                                   const u16* __restrict__ Wo,
                                                   const float* __restrict__ bo,
                                                   float* __restrict__ out) {
  __shared__ u16 As[128 * 64];
  __shared__ u16 Bs[128 * 64];
  const int tid = threadIdx.x, wave = tid >> 6, lane = tid & 63;
  const int lrow = lane & 15, lkg = lane >> 4;
  const int wm = wave >> 1, wn = wave & 1;
  const int bm0 = blockIdx.x * 128, bn0 = blockIdx.y * 128;

  f32x4 acc[4][4] = {};
  gemm_bt_core<16, ND, ND>(xh, Wo, As, Bs, acc, bm0, bn0, wave, lane);

#pragma unroll
  for (int i = 0; i < 4; ++i) {
#pragma unroll
    for (int j = 0; j < 4; ++j) {
      const int m0 = bm0 + wm * 64 + i * 16 + lkg * 4;
      const int n = bn0 + wn * 64 + j * 16 + lrow;
      const float bn_ = bo[n];
#pragma unroll
      for (int r = 0; r < 4; ++r)
        out[(size_t)(m0 + r) * ND + n] = acc[i][j][r] + bn_;
    }
  }
}

// ---------------- host launcher ----------------
extern "C" void kernel_launch(void* const* d_in, const int* in_sizes, int n_in,
                              void* d_out, int out_size, void* d_ws, size_t ws_size,
                              hipStream_t stream) {
  const float* Q = (const float*)d_in[0];
  const float* K = (const float*)d_in[1];
  const float* V = (const float*)d_in[2];
  // d_in[3] = mask (known causal tril; unused)
  const float* Wq = (const float*)d_in[4];
  const float* bq = (const float*)d_in[5];
  const float* Wk = (const float*)d_in[6];
  const float* bk = (const float*)d_in[7];
  const float* Wv = (const float*)d_in[8];
  const float* bv = (const float*)d_in[9];
  const float* Wo = (const float*)d_in[10];
  const float* bo = (const float*)d_in[11];

  // workspace layout (bytes), 64 MB total
  char* ws = (char*)d_ws;
  const size_t MB = 1u << 20;
  u16* Wq_b = (u16*)(ws + 0 * MB);
  u16* Wk_b = (u16*)(ws + 2 * MB);
  u16* Wv_b = (u16*)(ws + 4 * MB);
  u16* Wo_b = (u16*)(ws + 6 * MB);
  u16* Qb   = (u16*)(ws + 8 * MB);
  u16* Kb   = (u16*)(ws + 16 * MB);
  u16* Vb   = (u16*)(ws + 24 * MB);
  u16* qh   = (u16*)(ws + 32 * MB);  // [B,H,S,DK]
  u16* kh   = (u16*)(ws + 40 * MB);  // [B,H,S,DK]
  u16* vT   = (u16*)(ws + 48 * MB);  // [B,H,DK,S]
  u16* xh   = (u16*)(ws + 56 * MB);  // [B,S,D]

  float* out = (float*)d_out;                    // [B,S,D]
  float* attn = out + (size_t)NB * NS * ND;      // [B,H,S,S]

  // 1) convert inputs + weights to bf16
  CvtArgs ca;
  ca.src[0] = Q;  ca.dst[0] = Qb;   ca.n4[0] = (NB * NS * ND) / 4;
  ca.src[1] = K;  ca.dst[1] = Kb;   ca.n4[1] = (NB * NS * ND) / 4;
  ca.src[2] = V;  ca.dst[2] = Vb;   ca.n4[2] = (NB * NS * ND) / 4;
  ca.src[3] = Wq; ca.dst[3] = Wq_b; ca.n4[3] = (ND * ND) / 4;
  ca.src[4] = Wk; ca.dst[4] = Wk_b; ca.n4[4] = (ND * ND) / 4;
  ca.src[5] = Wv; ca.dst[5] = Wv_b; ca.n4[5] = (ND * ND) / 4;
  ca.src[6] = Wo; ca.dst[6] = Wo_b; ca.n4[6] = (ND * ND) / 4;
  cvt_k<<<dim3(512, 7), 256, 0, stream>>>(ca);

  // 2) QKV projections
  ProjArgs pa;
  pa.A[0] = Qb; pa.W[0] = Wq_b; pa.bias[0] = bq; pa.dst[0] = qh;
  pa.A[1] = Kb; pa.W[1] = Wk_b; pa.bias[1] = bk; pa.dst[1] = kh;
  pa.A[2] = Vb; pa.W[2] = Wv_b; pa.bias[2] = bv; pa.dst[2] = vT;
  proj_gemm<<<dim3((NB * NS) / 128, ND / 128, 3), 256, 0, stream>>>(pa);

  // 3) raw scores into d_out attn region (lower-tri blocks)
  qk_gemm<<<dim3(NS / 128, NS / 128, NBH), 256, 0, stream>>>(qh, kh, attn);

  // 4) causal softmax in place (writes full rows incl. zeros for k>q)
  softmax_k<<<dim3((NBH * NS) / 4), 256, 0, stream>>>(attn);

  // 5) x = attn @ v
  pv_gemm<<<dim3(NS / 128, NBH), 256, 0, stream>>>(attn, vT, xh);

  // 6) out = x @ Wo^T + bo
  out_gemm<<<dim3((NB * NS) / 128, ND / 128), 256, 0, stream>>>(xh, Wo_b, bo, out);
}

// Round 2
// 186.965 us; speedup vs baseline: 1.6296x; 1.6296x over previous
//
#include <hip/hip_runtime.h>
#include <hip/hip_bf16.h>
#include <cstdint>

// Problem: B=4, S=1024, D=1024, H=16, DK=64.
// Outputs: out [4,1024,1024] f32, attn [4,16,1024,1024] f32, concatenated in d_out.
#define NB 4
#define NS 1024
#define ND 1024
#define NH 16
#define NDK 64
#define NBH 64  // NB*NH

typedef unsigned short u16;
typedef __attribute__((ext_vector_type(8))) short short8;   // 8 x bf16 bits (4 VGPRs) - MFMA A/B frag
typedef __attribute__((ext_vector_type(4))) float f32x4;    // MFMA C/D frag
typedef __attribute__((ext_vector_type(4))) unsigned short u16x4;

// u16-index XOR swizzle (bits 3-5 <-> byte bits 4-6), valid for any 4-aligned col
#define SWZ(r, c) ((c) ^ (((r) & 7) << 3))

__device__ __forceinline__ u16 f2bf(float x) {
  unsigned u = __builtin_bit_cast(unsigned, x);
  return (u16)((u + 0x7fffu + ((u >> 16) & 1u)) >> 16);  // RNE
}
__device__ __forceinline__ float bf2f(u16 b) {
  return __builtin_bit_cast(float, ((unsigned)b) << 16);
}

__device__ __forceinline__ void async16(u16* lds_dst, const u16* gsrc) {
  // global -> LDS direct copy, 16B per lane; lds_dst must be wave-uniform.
  __builtin_amdgcn_global_load_lds(
      (const __attribute__((address_space(1))) void*)gsrc,
      (__attribute__((address_space(3))) void*)lds_dst, 16, 0, 0);
}

// Stage a 64x64 bf16 tile (8KB) with one 4-wave group; LDS content is
// XOR-swizzled by pre-swizzling the per-lane GLOBAL source (dest stays linear).
__device__ __forceinline__ void stage64(u16* dst, const u16* src, int ld, int w4, int lane) {
#pragma unroll
  for (int j = 0; j < 2; ++j) {
    const int chunk = w4 * 128 + j * 64 + lane;   // 16B chunk id in [0,512)
    const int row = chunk >> 3, scol = chunk & 7;
    const int gc = scol ^ (row & 7);
    async16(dst + (w4 * 128 + j * 64) * 8, src + (size_t)row * ld + gc * 8);
  }
}

// ---------------- f32 -> bf16 conversion prepass ----------------
struct CvtArgs {
  const float* src[7];
  u16* dst[7];
  int n4[7];
};

__global__ __launch_bounds__(256) void cvt_k(CvtArgs a) {
  const int seg = blockIdx.y;
  const float* s = a.src[seg];
  u16* d = a.dst[seg];
  const int n4 = a.n4[seg];
  for (int i = blockIdx.x * 256 + threadIdx.x; i < n4; i += gridDim.x * 256) {
    float4 v = *(const float4*)&s[(size_t)i * 4];
    u16x4 pk = {f2bf(v.x), f2bf(v.y), f2bf(v.z), f2bf(v.w)};
    *(u16x4*)&d[(size_t)i * 4] = pk;
  }
}

// ---------------- common GEMM-BT core: 128x128 tile, BK=64, 4 waves (2x2) ----------------
template <int KTILES, int LDA, int LDB>
__device__ __forceinline__ void gemm_bt_core(const u16* __restrict__ A,
                                             const u16* __restrict__ BT,
                                             u16* As, u16* Bs, f32x4 (&acc)[4][4],
                                             int bm0, int bn0, int wave, int lane) {
  const int lrow = lane & 15;
  const int lkg = lane >> 4;
  const int wm = wave >> 1, wn = wave & 1;
#pragma unroll 1
  for (int t = 0; t < KTILES; ++t) {
    const int k0 = t * 64;
#pragma unroll
    for (int j = 0; j < 4; ++j) {
      const int c = (wave * 4 + j) * 64 + lane;
      const int row = c >> 3;
      const int col = (c & 7) * 8;
      async16(&As[(wave * 4 + j) * 512], A + (size_t)(bm0 + row) * LDA + k0 + col);
      async16(&Bs[(wave * 4 + j) * 512], BT + (size_t)(bn0 + row) * LDB + k0 + col);
    }
    asm volatile("s_waitcnt vmcnt(0)" ::: "memory");
    __syncthreads();
#pragma unroll
    for (int kk = 0; kk < 2; ++kk) {
      short8 av[4], bv[4];
#pragma unroll
      for (int i = 0; i < 4; ++i)
        av[i] = *(const short8*)&As[(wm * 64 + i * 16 + lrow) * 64 + kk * 32 + lkg * 8];
#pragma unroll
      for (int j = 0; j < 4; ++j)
        bv[j] = *(const short8*)&Bs[(wn * 64 + j * 16 + lrow) * 64 + kk * 32 + lkg * 8];
#pragma unroll
      for (int i = 0; i < 4; ++i)
#pragma unroll
        for (int j = 0; j < 4; ++j)
          acc[i][j] = __builtin_amdgcn_mfma_f32_16x16x32_bf16(av[i], bv[j], acc[i][j], 0, 0, 0);
    }
    __syncthreads();
  }
}

// ---------------- QKV projection (z = 0:q, 1:k, 2:v) ----------------
struct ProjArgs {
  const u16* A[3];
  const u16* W[3];
  const float* bias[3];
  u16* dst[3];
};

__global__ __launch_bounds__(256, 2) void proj_gemm(ProjArgs pa) {
  const int z = blockIdx.z;
  const u16* A = pa.A[z];
  const u16* BT = pa.W[z];
  const float* bias = pa.bias[z];
  u16* dst = pa.dst[z];

  __shared__ u16 As[128 * 64];
  __shared__ u16 Bs[128 * 64];
  const int tid = threadIdx.x, wave = tid >> 6, lane = tid & 63;
  const int lrow = lane & 15, lkg = lane >> 4;
  const int wm = wave >> 1, wn = wave & 1;
  const int bm0 = blockIdx.x * 128, bn0 = blockIdx.y * 128;

  f32x4 acc[4][4] = {};
  gemm_bt_core<16, ND, ND>(A, BT, As, Bs, acc, bm0, bn0, wave, lane);

#pragma unroll
  for (int i = 0; i < 4; ++i) {
#pragma unroll
    for (int j = 0; j < 4; ++j) {
      const int m0 = bm0 + wm * 64 + i * 16 + lkg * 4;
      const int n = bn0 + wn * 64 + j * 16 + lrow;
      const float bn_ = bias[n];
      const int b = m0 >> 10;
      const int h = n >> 6, dk = n & 63;
      if (z < 2) {
        // q/k head layout: [B,H,S,DK]
#pragma unroll
        for (int r = 0; r < 4; ++r) {
          const int s = (m0 + r) & 1023;
          dst[(((size_t)(b * NH + h)) * NS + s) * NDK + dk] = f2bf(acc[i][j][r] + bn_);
        }
      } else {
        // v transposed: [B,H,DK,S]
        const int s0 = m0 & 1023;
        u16x4 pk;
#pragma unroll
        for (int r = 0; r < 4; ++r) pk[r] = f2bf(acc[i][j][r] + bn_);
        *(u16x4*)&dst[(((size_t)(b * NH + h)) * NDK + dk) * NS + s0] = pk;
      }
    }
  }
}

// ---------------- fused attention: scores + causal softmax + PV ----------------
// One block per (bh, 64-row q-strip). 8 waves = 2 groups of 4; groups process
// even/odd K/V tiles with per-group double-buffered LDS staging.
// Score strip lives in LDS (bf16, XOR-swizzled). attn written once (f32).
__global__ __launch_bounds__(512, 2) void attn_fused(
    const u16* __restrict__ qh, const u16* __restrict__ kh,
    const u16* __restrict__ vT, float* __restrict__ attn,
    u16* __restrict__ xh) {
  __shared__ __align__(16) char smem_raw[163840];  // 160KB exactly
  u16* sc = (u16*)smem_raw;                        // [64][1024] bf16, swizzled (128KB)
  u16* kb = (u16*)(smem_raw + 131072);             // 4 x 8KB K/V staging
  float* m_arr = (float*)(smem_raw + 131072);      // [64] alias (between QK and PV)
  float* xmerge = (float*)(smem_raw + 131072);     // [64][65] f32 alias (after PV)

  const int tid = threadIdx.x;
  const int wave = tid >> 6, lane = tid & 63;
  const int lrow = lane & 15, lkg = lane >> 4;
  const int g = wave >> 2, w4 = wave & 3;
  const int mt = 15 - (int)blockIdx.x;  // big strips first for scheduling
  const int bh = blockIdx.y;
  const int s0 = mt * 64;
  const int nkt = mt + 1;               // causal K/V tiles of 64
  const int nk = nkt * 64;
  const u16* Qb = qh + (size_t)bh * NS * NDK;
  const u16* Kb = kh + (size_t)bh * NS * NDK;
  const u16* Vb = vT + (size_t)bh * NS * NDK;  // [DK][S]
  float* attn_s = attn + (size_t)bh * NS * NS + (size_t)s0 * NS;

  // ---- stage Q strip (8KB) into kb[2..3] region, swizzled; hoist to regs
  {
    const int row = tid >> 3, scol = tid & 7;
    const int gc = scol ^ (row & 7);
    async16(kb + 2 * 4096 + wave * 512, Qb + (size_t)(s0 + row) * NDK + gc * 8);
    asm volatile("s_waitcnt vmcnt(0)" ::: "memory");
    __syncthreads();
  }
  short8 qv[2];
  {
    const int q = w4 * 16 + lrow;
#pragma unroll
    for (int kk = 0; kk < 2; ++kk)
      qv[kk] = *(const short8*)&kb[2 * 4096 + q * 64 + SWZ(q, kk * 32 + lkg * 8)];
  }
  __syncthreads();

  // ---- QK phase: D[k][q] per tile (swapped operands -> lane owns one q-row)
  float m_run = -3e38f;
  const int npairs = (nkt + 1) >> 1;
  if (g < nkt) stage64(kb + (g * 2) * 4096, Kb + (size_t)g * 64 * NDK, NDK, w4, lane);
#pragma unroll 1
  for (int p = 0; p < npairs; ++p) {
    const int kt = 2 * p + g;
    const int ktn = kt + 2;
    const bool haven = ktn < nkt;
    if (haven)
      stage64(kb + (g * 2 + ((p + 1) & 1)) * 4096, Kb + (size_t)ktn * 64 * NDK, NDK, w4, lane);
    if (haven) asm volatile("s_waitcnt vmcnt(2)" ::: "memory");
    else       asm volatile("s_waitcnt vmcnt(0)" ::: "memory");
    __builtin_amdgcn_s_barrier();
    if (kt < nkt) {
      const u16* kbuf = kb + (g * 2 + (p & 1)) * 4096;
      f32x4 acc[4] = {};
#pragma unroll
      for (int kk = 0; kk < 2; ++kk) {
        short8 av[4];
#pragma unroll
        for (int i = 0; i < 4; ++i) {
          const int r = i * 16 + lrow;
          av[i] = *(const short8*)&kbuf[r * 64 + SWZ(r, kk * 32 + lkg * 8)];
        }
#pragma unroll
        for (int i = 0; i < 4; ++i)
          acc[i] = __builtin_amdgcn_mfma_f32_16x16x32_bf16(av[i], qv[kk], acc[i], 0, 0, 0);
      }
      const int qloc = w4 * 16 + lrow;
      const int qg = s0 + qloc;
#pragma unroll
      for (int i = 0; i < 4; ++i) {
        u16x4 pk;
#pragma unroll
        for (int r = 0; r < 4; ++r) {
          float s = acc[i][r] * 0.125f;  // 1/sqrt(DK)
          const int kg = kt * 64 + i * 16 + lkg * 4 + r;
          if (kg > qg) s = -1e30f;       // causal mask
          m_run = fmaxf(m_run, s);
          pk[r] = f2bf(s);
        }
        const int c = kt * 64 + i * 16 + lkg * 4;
        *(u16x4*)&sc[qloc * 1024 + SWZ(qloc, c)] = pk;
      }
    }
    __builtin_amdgcn_s_barrier();
  }
  __syncthreads();

  // ---- merge row-max across the two groups (same q-cols in wave w and w+4)
  if (g == 0 && lkg == 0) m_arr[w4 * 16 + lrow] = m_run;
  __syncthreads();
  if (g == 1 && lkg == 0) {
    float* mp = &m_arr[w4 * 16 + lrow];
    *mp = fmaxf(*mp, m_run);
  }
  __syncthreads();

  // ---- per-wave rows: exp + sum, then normalize + single f32 attn write
#pragma unroll 1
  for (int rr = 0; rr < 8; ++rr) {
    const int q = wave * 8 + rr;
    const float m = m_arr[q];
    float part = 0.f;
#pragma unroll 1
    for (int c0 = 0; c0 < nk; c0 += 256) {
      const int c = c0 + lane * 4;
      if (c < nk) {
        u16x4 e4 = *(u16x4*)&sc[q * 1024 + SWZ(q, c)];
        u16x4 pk;
#pragma unroll
        for (int e = 0; e < 4; ++e) {
          const float pe = __expf(bf2f(e4[e]) - m);
          part += pe;
          pk[e] = f2bf(pe);
        }
        *(u16x4*)&sc[q * 1024 + SWZ(q, c)] = pk;
      }
    }
#pragma unroll
    for (int o = 32; o; o >>= 1) part += __shfl_xor(part, o, 64);
    const float inv = 1.0f / part;
#pragma unroll 1
    for (int c0 = 0; c0 < NS; c0 += 256) {
      const int c = c0 + lane * 4;
      float4 o4 = {0.f, 0.f, 0.f, 0.f};
      if (c < nk) {
        u16x4 e4 = *(u16x4*)&sc[q * 1024 + SWZ(q, c)];
        u16x4 pn;
#pragma unroll
        for (int e = 0; e < 4; ++e) {
          const float pe = bf2f(e4[e]) * inv;
          ((float*)&o4)[e] = pe;
          pn[e] = f2bf(pe);
        }
        *(u16x4*)&sc[q * 1024 + SWZ(q, c)] = pn;  // normalized bf16 P for PV
      }
      *(float4*)&attn_s[(size_t)q * NS + c] = o4;  // includes causal zeros
    }
  }
  __syncthreads();

  // ---- PV phase: x[64q][64dk] = P @ V, tiles split even/odd across groups
  f32x4 xacc[4] = {};
  if (g < nkt) stage64(kb + (g * 2) * 4096, Vb + (size_t)g * 64, NS, w4, lane);
#pragma unroll 1
  for (int p = 0; p < npairs; ++p) {
    const int kt = 2 * p + g;
    const int ktn = kt + 2;
    const bool haven = ktn < nkt;
    if (haven)
      stage64(kb + (g * 2 + ((p + 1) & 1)) * 4096, Vb + (size_t)ktn * 64, NS, w4, lane);
    if (haven) asm volatile("s_waitcnt vmcnt(2)" ::: "memory");
    else       asm volatile("s_waitcnt vmcnt(0)" ::: "memory");
    __builtin_amdgcn_s_barrier();
    if (kt < nkt) {
      const u16* vbuf = kb + (g * 2 + (p & 1)) * 4096;
      const int qrow = w4 * 16 + lrow;
#pragma unroll
      for (int kk = 0; kk < 2; ++kk) {
        short8 av = *(const short8*)&sc[qrow * 1024 + SWZ(qrow, kt * 64 + kk * 32 + lkg * 8)];
        short8 bv[4];
#pragma unroll
        for (int j = 0; j < 4; ++j) {
          const int r = j * 16 + lrow;
          bv[j] = *(const short8*)&vbuf[r * 64 + SWZ(r, kk * 32 + lkg * 8)];
        }
#pragma unroll
        for (int j = 0; j < 4; ++j)
          xacc[j] = __builtin_amdgcn_mfma_f32_16x16x32_bf16(av, bv[j], xacc[j], 0, 0, 0);
      }
    }
    __builtin_amdgcn_s_barrier();
  }
  __syncthreads();

  // ---- cross-group merge + epilogue to xh [B,S,D] bf16
  if (g == 1) {
#pragma unroll
    for (int j = 0; j < 4; ++j) {
      const int dk = j * 16 + lrow;
#pragma unroll
      for (int r = 0; r < 4; ++r) {
        const int q = w4 * 16 + lkg * 4 + r;
        xmerge[q * 65 + dk] = xacc[j][r];
      }
    }
  }
  __syncthreads();
  if (g == 0) {
    const int b = bh >> 4, h = bh & 15;
#pragma unroll
    for (int j = 0; j < 4; ++j) {
      const int dk = j * 16 + lrow;
#pragma unroll
      for (int r = 0; r < 4; ++r) {
        const int q = w4 * 16 + lkg * 4 + r;
        const float x = xacc[j][r] + xmerge[q * 65 + dk];
        xh[(size_t)(b * NS + s0 + q) * ND + h * NDK + dk] = f2bf(x);
      }
    }
  }
}

// ---------------- out = x @ Wo^T + bo ----------------
__global__ __launch_bounds__(256, 2) void out_gemm(const u16* __restrict__ xh,
                                                   const u16* __restrict__ Wo,
                                                   const float* __restrict__ bo,
                                                   float* __restrict__ out) {
  __shared__ u16 As[128 * 64];
  __shared__ u16 Bs[128 * 64];
  const int tid = threadIdx.x, wave = tid >> 6, lane = tid & 63;
  const int lrow = lane & 15, lkg = lane >> 4;
  const int wm = wave >> 1, wn = wave & 1;
  const int bm0 = blockIdx.x * 128, bn0 = blockIdx.y * 128;

  f32x4 acc[4][4] = {};
  gemm_bt_core<16, ND, ND>(xh, Wo, As, Bs, acc, bm0, bn0, wave, lane);

#pragma unroll
  for (int i = 0; i < 4; ++i) {
#pragma unroll
    for (int j = 0; j < 4; ++j) {
      const int m0 = bm0 + wm * 64 + i * 16 + lkg * 4;
      const int n = bn0 + wn * 64 + j * 16 + lrow;
      const float bn_ = bo[n];
#pragma unroll
      for (int r = 0; r < 4; ++r)
        out[(size_t)(m0 + r) * ND + n] = acc[i][j][r] + bn_;
    }
  }
}

// ---------------- host launcher ----------------
extern "C" void kernel_launch(void* const* d_in, const int* in_sizes, int n_in,
                              void* d_out, int out_size, void* d_ws, size_t ws_size,
                              hipStream_t stream) {
  const float* Q = (const float*)d_in[0];
  const float* K = (const float*)d_in[1];
  const float* V = (const float*)d_in[2];
  // d_in[3] = mask (known causal tril; unused)
  const float* Wq = (const float*)d_in[4];
  const float* bq = (const float*)d_in[5];
  const float* Wk = (const float*)d_in[6];
  const float* bk = (const float*)d_in[7];
  const float* Wv = (const float*)d_in[8];
  const float* bv = (const float*)d_in[9];
  const float* Wo = (const float*)d_in[10];
  const float* bo = (const float*)d_in[11];

  char* ws = (char*)d_ws;
  const size_t MB = 1u << 20;
  u16* Wq_b = (u16*)(ws + 0 * MB);
  u16* Wk_b = (u16*)(ws + 2 * MB);
  u16* Wv_b = (u16*)(ws + 4 * MB);
  u16* Wo_b = (u16*)(ws + 6 * MB);
  u16* Qb   = (u16*)(ws + 8 * MB);
  u16* Kb   = (u16*)(ws + 16 * MB);
  u16* Vb   = (u16*)(ws + 24 * MB);
  u16* qh   = (u16*)(ws + 32 * MB);  // [B,H,S,DK]
  u16* kh   = (u16*)(ws + 40 * MB);  // [B,H,S,DK]
  u16* vT   = (u16*)(ws + 48 * MB);  // [B,H,DK,S]
  u16* xh   = (u16*)(ws + 56 * MB);  // [B,S,D]

  float* out = (float*)d_out;                 // [B,S,D]
  float* attn = out + (size_t)NB * NS * ND;   // [B,H,S,S]

  CvtArgs ca;
  ca.src[0] = Q;  ca.dst[0] = Qb;   ca.n4[0] = (NB * NS * ND) / 4;
  ca.src[1] = K;  ca.dst[1] = Kb;   ca.n4[1] = (NB * NS * ND) / 4;
  ca.src[2] = V;  ca.dst[2] = Vb;   ca.n4[2] = (NB * NS * ND) / 4;
  ca.src[3] = Wq; ca.dst[3] = Wq_b; ca.n4[3] = (ND * ND) / 4;
  ca.src[4] = Wk; ca.dst[4] = Wk_b; ca.n4[4] = (ND * ND) / 4;
  ca.src[5] = Wv; ca.dst[5] = Wv_b; ca.n4[5] = (ND * ND) / 4;
  ca.src[6] = Wo; ca.dst[6] = Wo_b; ca.n4[6] = (ND * ND) / 4;
  cvt_k<<<dim3(512, 7), 256, 0, stream>>>(ca);

  ProjArgs pa;
  pa.A[0] = Qb; pa.W[0] = Wq_b; pa.bias[0] = bq; pa.dst[0] = qh;
  pa.A[1] = Kb; pa.W[1] = Wk_b; pa.bias[1] = bk; pa.dst[1] = kh;
  pa.A[2] = Vb; pa.W[2] = Wv_b; pa.bias[2] = bv; pa.dst[2] = vT;
  proj_gemm<<<dim3((NB * NS) / 128, ND / 128, 3), 256, 0, stream>>>(pa);

  // fused scores + softmax + PV; writes attn (f32) once and xh (bf16)
  attn_fused<<<dim3(16, NBH), 512, 0, stream>>>(qh, kh, vT, attn, xh);

  out_gemm<<<dim3((NB * NS) / 128, ND / 128), 256, 0, stream>>>(xh, Wo_b, bo, out);
}